// Round 2
// baseline (1056.907 us; speedup 1.0000x reference)
//
#include <hip/hip_runtime.h>
#include <hip/hip_fp16.h>

#define N_NODES  100000
#define N_EDGES  3200000
#define N_GRAPHS 64

#define BSHIFT   7
#define NBUCK    782          // ceil(N_NODES / 128)
#define CAP      4608         // mean 4096 + 8 sigma; overflow guarded (dropped)

#define SCALE1   2097152.0f   // 2^21 fixed-point for layer-1 accumulation
#define ISCALE1  (1.0f / 2097152.0f)
#define SCALE2   1048576.0f   // 2^20 for layer-2 (post-relu sums are larger)
#define ISCALE2  (1.0f / 1048576.0f)
#define SCALEP   65536.0f     // 2^16 for pooling partial sums (int LDS atomics)
#define ISCALEP  (1.0f / 65536.0f)

// R15: int fixed-point accumulation is order-independent -> deterministic
// binning (hist+scan+place, 3 kernels) replaced by ONE atomic-slot pass.
// degG counted here too (deletes bucket_dinv; also matches reference: degree
// counts ALL edges). R14 MLP batching widened 8 -> 16 edges/quad in gathers.

// shared edge-accumulate body for gather1/gather2 (int fixed-point LDS atomics)
#define EDGEACC(p_, r_, SC) { \
    int d_ = (int)((p_) >> 17); \
    float2 f01_ = __half22float2(*(const __half2*)&(r_).x); \
    float2 f23_ = __half22float2(*(const __half2*)&(r_).y); \
    int* a_ = &acc[d_ * 17 + f4 * 4]; \
    atomicAdd(a_ + 0, __float2int_rn(f01_.x * (SC))); \
    atomicAdd(a_ + 1, __float2int_rn(f01_.y * (SC))); \
    atomicAdd(a_ + 2, __float2int_rn(f23_.x * (SC))); \
    atomicAdd(a_ + 3, __float2int_rn(f23_.y * (SC))); }

// ---------------- single-pass binning: slot via global atomic, deg count ----
__global__ void __launch_bounds__(256) place_direct(const int* __restrict__ src,
                                                    const int* __restrict__ dst,
                                                    unsigned int* __restrict__ stage,
                                                    int* __restrict__ degG,
                                                    int* __restrict__ bcnt) {
    int e4 = blockIdx.x * 256 + threadIdx.x;        // 4 edges per thread, exact
    int4 d = *(const int4*)(dst + e4 * 4);
    int4 s = *(const int4*)(src + e4 * 4);
    atomicAdd(&degG[d.x], 1);                        // fire-and-forget
    atomicAdd(&degG[d.y], 1);
    atomicAdd(&degG[d.z], 1);
    atomicAdd(&degG[d.w], 1);
    int bx = d.x >> BSHIFT, by = d.y >> BSHIFT;
    int bz = d.z >> BSHIFT, bw = d.w >> BSHIFT;
    int sx = atomicAdd(&bcnt[bx], 1);                // returning atomics
    int sy = atomicAdd(&bcnt[by], 1);
    int sz = atomicAdd(&bcnt[bz], 1);
    int sw = atomicAdd(&bcnt[bw], 1);
    if (sx < CAP) stage[bx * CAP + sx] = ((unsigned)(d.x & 127) << 17) | (unsigned)s.x;
    if (sy < CAP) stage[by * CAP + sy] = ((unsigned)(d.y & 127) << 17) | (unsigned)s.y;
    if (sz < CAP) stage[bz * CAP + sz] = ((unsigned)(d.z & 127) << 17) | (unsigned)s.z;
    if (sw < CAP) stage[bw * CAP + sw] = ((unsigned)(d.w & 127) << 17) | (unsigned)s.w;
}

// ---------------- layer-1 matmul: hs1 = fp16( (x @ W1) * dinv ), dinv from degG
// R15: 64 rows/block, 4 outputs/thread via b128 W reads (4x fewer LDS instrs).
#define MM1_ROWS 64
__global__ void __launch_bounds__(256) mm1(const float* __restrict__ x,
                                           const float* __restrict__ W,
                                           const int* __restrict__ degG,
                                           float* __restrict__ dinv,
                                           __half* __restrict__ hs) {
    __shared__ float ws[128 * 16];
    __shared__ float xs[MM1_ROWS * 132];   // pad 132: 16B-aligned, 2-way bank (free)
    int t = threadIdx.x;
    int row0 = blockIdx.x * MM1_ROWS;
    for (int i = t; i < 2048; i += 256) ws[i] = W[i];
    for (int i = t; i < 2048; i += 256) {             // 2048 float4 = 64 rows x 128
        int r = i >> 5, c4 = (i & 31) * 4;
        int v = row0 + r;
        float4 val = (v < N_NODES) ? *(const float4*)(x + (size_t)v * 128 + c4)
                                   : make_float4(0.f, 0.f, 0.f, 0.f);
        *(float4*)&xs[r * 132 + c4] = val;
    }
    __syncthreads();
    int row = t >> 2, c4 = (t & 3) * 4;
    int v = row0 + row;
    if (v < N_NODES) {
        float dv = rsqrtf((float)(degG[v] + 1));      // +1 self loop
        if (c4 == 0) dinv[v] = dv;
        float a0 = 0.f, a1 = 0.f, a2 = 0.f, a3 = 0.f;
#pragma unroll
        for (int k = 0; k < 128; k++) {
            float xv = xs[row * 132 + k];
            float4 w4 = *(const float4*)&ws[k * 16 + c4];
            a0 += xv * w4.x; a1 += xv * w4.y; a2 += xv * w4.z; a3 += xv * w4.w;
        }
        __half2 h01 = __floats2half2_rn(a0 * dv, a1 * dv);
        __half2 h23 = __floats2half2_rn(a2 * dv, a3 * dv);
        uint2 o = make_uint2(*(unsigned*)&h01, *(unsigned*)&h23);
        *(uint2*)(hs + (size_t)v * 16 + c4) = o;      // 8B store
    }
}

// ---------------- layer-1 gather: edge-parallel, FIXED-POINT int LDS atomics --
// R13: int atomicAdd is native ds_add_u32. R15: 16-edge batching per quad.
__global__ void __launch_bounds__(256) gather1(const unsigned int* __restrict__ stage,
                                               const int* __restrict__ cntG,
                                               const __half* __restrict__ hs,
                                               const float* __restrict__ dinv,
                                               const float* __restrict__ b1,
                                               __half* __restrict__ d1) {
    __shared__ int acc[128 * 17];   // +1 pad spreads d*16 bank aliasing
    int b = blockIdx.x, t = threadIdx.x;
    int base = b * CAP;
    int cnt = cntG[b]; if (cnt > CAP) cnt = CAP;
    for (int i = t; i < 128 * 17; i += 256) acc[i] = 0;
    __syncthreads();
    int f4 = t & 3;
    int q = t >> 2;
    int i0 = q * 16;
    for (; i0 + 16 <= cnt; i0 += 1024) {
        const uint4* sp = (const uint4*)(stage + base + i0);  // 16B-aligned
        uint4 pa = sp[0], pb = sp[1], pc = sp[2], pd = sp[3]; // quad-broadcast
        uint2 r0  = *(const uint2*)(hs + (pa.x & 0x1FFFF) * 16 + f4 * 4);
        uint2 r1  = *(const uint2*)(hs + (pa.y & 0x1FFFF) * 16 + f4 * 4);
        uint2 r2  = *(const uint2*)(hs + (pa.z & 0x1FFFF) * 16 + f4 * 4);
        uint2 r3  = *(const uint2*)(hs + (pa.w & 0x1FFFF) * 16 + f4 * 4);
        uint2 r4  = *(const uint2*)(hs + (pb.x & 0x1FFFF) * 16 + f4 * 4);
        uint2 r5  = *(const uint2*)(hs + (pb.y & 0x1FFFF) * 16 + f4 * 4);
        uint2 r6  = *(const uint2*)(hs + (pb.z & 0x1FFFF) * 16 + f4 * 4);
        uint2 r7  = *(const uint2*)(hs + (pb.w & 0x1FFFF) * 16 + f4 * 4);
        uint2 r8  = *(const uint2*)(hs + (pc.x & 0x1FFFF) * 16 + f4 * 4);
        uint2 r9  = *(const uint2*)(hs + (pc.y & 0x1FFFF) * 16 + f4 * 4);
        uint2 r10 = *(const uint2*)(hs + (pc.z & 0x1FFFF) * 16 + f4 * 4);
        uint2 r11 = *(const uint2*)(hs + (pc.w & 0x1FFFF) * 16 + f4 * 4);
        uint2 r12 = *(const uint2*)(hs + (pd.x & 0x1FFFF) * 16 + f4 * 4);
        uint2 r13 = *(const uint2*)(hs + (pd.y & 0x1FFFF) * 16 + f4 * 4);
        uint2 r14 = *(const uint2*)(hs + (pd.z & 0x1FFFF) * 16 + f4 * 4);
        uint2 r15 = *(const uint2*)(hs + (pd.w & 0x1FFFF) * 16 + f4 * 4);
        EDGEACC(pa.x, r0,  SCALE1); EDGEACC(pa.y, r1,  SCALE1);
        EDGEACC(pa.z, r2,  SCALE1); EDGEACC(pa.w, r3,  SCALE1);
        EDGEACC(pb.x, r4,  SCALE1); EDGEACC(pb.y, r5,  SCALE1);
        EDGEACC(pb.z, r6,  SCALE1); EDGEACC(pb.w, r7,  SCALE1);
        EDGEACC(pc.x, r8,  SCALE1); EDGEACC(pc.y, r9,  SCALE1);
        EDGEACC(pc.z, r10, SCALE1); EDGEACC(pc.w, r11, SCALE1);
        EDGEACC(pd.x, r12, SCALE1); EDGEACC(pd.y, r13, SCALE1);
        EDGEACC(pd.z, r14, SCALE1); EDGEACC(pd.w, r15, SCALE1);
    }
    for (int j = i0; j < cnt && j < i0 + 16; j++) {           // residual window
        unsigned int p = stage[base + j];
        uint2 r = *(const uint2*)(hs + (p & 0x1FFFF) * 16 + f4 * 4);
        EDGEACC(p, r, SCALE1);
    }
    __syncthreads();
    for (int i = t; i < 2048; i += 256) {
        int n = i >> 4, k = i & 15, v = b * 128 + n;
        if (v < N_NODES) {
            float dv = dinv[v];
            float sum = (float)acc[n * 17 + k] * ISCALE1;
            float self = __half2float(hs[v * 16 + k]);
            float r = dv * (sum + self) + b1[k];
            d1[v * 16 + k] = __float2half(r > 0.f ? dv * r : 0.f);
        }
    }
}

// ---------------- layer-2 gather + mm2 + relu + mean-pool, fused --------------
__global__ void __launch_bounds__(256) gather2(const unsigned int* __restrict__ stage,
                                               const int* __restrict__ cntG,
                                               const __half* __restrict__ d1,
                                               const float* __restrict__ dinv,
                                               const float* __restrict__ W2,
                                               const float* __restrict__ b2,
                                               const int* __restrict__ batch,
                                               float* __restrict__ gsum,
                                               float* __restrict__ gcnt) {
    __shared__ int acc[128 * 17];
    __shared__ float wl[512];
    __shared__ int lsum[N_GRAPHS * 32];   // int fixed-point (native ds_add)
    __shared__ int lcnt[N_GRAPHS];
    __shared__ int lbat[128];
    float* accf = (float*)acc;   // reused as float after conversion pass
    int b = blockIdx.x, t = threadIdx.x;
    int base = b * CAP;
    int cnt = cntG[b]; if (cnt > CAP) cnt = CAP;
    for (int i = t; i < 128 * 17; i += 256) acc[i] = 0;
    for (int i = t; i < 512; i += 256) wl[i] = W2[i];
    for (int i = t; i < N_GRAPHS * 32; i += 256) lsum[i] = 0;
    if (t < N_GRAPHS) lcnt[t] = 0;
    if (t < 128) {
        int v = b * 128 + t;
        lbat[t] = (v < N_NODES) ? batch[v] : 0;
    }
    __syncthreads();
    int f4 = t & 3;
    int q = t >> 2;
    int i0 = q * 16;
    for (; i0 + 16 <= cnt; i0 += 1024) {
        const uint4* sp = (const uint4*)(stage + base + i0);
        uint4 pa = sp[0], pb = sp[1], pc = sp[2], pd = sp[3];
        uint2 r0  = *(const uint2*)(d1 + (pa.x & 0x1FFFF) * 16 + f4 * 4);
        uint2 r1  = *(const uint2*)(d1 + (pa.y & 0x1FFFF) * 16 + f4 * 4);
        uint2 r2  = *(const uint2*)(d1 + (pa.z & 0x1FFFF) * 16 + f4 * 4);
        uint2 r3  = *(const uint2*)(d1 + (pa.w & 0x1FFFF) * 16 + f4 * 4);
        uint2 r4  = *(const uint2*)(d1 + (pb.x & 0x1FFFF) * 16 + f4 * 4);
        uint2 r5  = *(const uint2*)(d1 + (pb.y & 0x1FFFF) * 16 + f4 * 4);
        uint2 r6  = *(const uint2*)(d1 + (pb.z & 0x1FFFF) * 16 + f4 * 4);
        uint2 r7  = *(const uint2*)(d1 + (pb.w & 0x1FFFF) * 16 + f4 * 4);
        uint2 r8  = *(const uint2*)(d1 + (pc.x & 0x1FFFF) * 16 + f4 * 4);
        uint2 r9  = *(const uint2*)(d1 + (pc.y & 0x1FFFF) * 16 + f4 * 4);
        uint2 r10 = *(const uint2*)(d1 + (pc.z & 0x1FFFF) * 16 + f4 * 4);
        uint2 r11 = *(const uint2*)(d1 + (pc.w & 0x1FFFF) * 16 + f4 * 4);
        uint2 r12 = *(const uint2*)(d1 + (pd.x & 0x1FFFF) * 16 + f4 * 4);
        uint2 r13 = *(const uint2*)(d1 + (pd.y & 0x1FFFF) * 16 + f4 * 4);
        uint2 r14 = *(const uint2*)(d1 + (pd.z & 0x1FFFF) * 16 + f4 * 4);
        uint2 r15 = *(const uint2*)(d1 + (pd.w & 0x1FFFF) * 16 + f4 * 4);
        EDGEACC(pa.x, r0,  SCALE2); EDGEACC(pa.y, r1,  SCALE2);
        EDGEACC(pa.z, r2,  SCALE2); EDGEACC(pa.w, r3,  SCALE2);
        EDGEACC(pb.x, r4,  SCALE2); EDGEACC(pb.y, r5,  SCALE2);
        EDGEACC(pb.z, r6,  SCALE2); EDGEACC(pb.w, r7,  SCALE2);
        EDGEACC(pc.x, r8,  SCALE2); EDGEACC(pc.y, r9,  SCALE2);
        EDGEACC(pc.z, r10, SCALE2); EDGEACC(pc.w, r11, SCALE2);
        EDGEACC(pd.x, r12, SCALE2); EDGEACC(pd.y, r13, SCALE2);
        EDGEACC(pd.z, r14, SCALE2); EDGEACC(pd.w, r15, SCALE2);
    }
    for (int j = i0; j < cnt && j < i0 + 16; j++) {
        unsigned int p = stage[base + j];
        uint2 r = *(const uint2*)(d1 + (p & 0x1FFFF) * 16 + f4 * 4);
        EDGEACC(p, r, SCALE2);
    }
    __syncthreads();
    // convert int->float in place and add self-loop term
    for (int i = t; i < 2048; i += 256) {
        int n = i >> 4, k = i & 15, v = b * 128 + n;
        float sum = (float)acc[n * 17 + k] * ISCALE2;
        if (v < N_NODES) sum += __half2float(d1[v * 16 + k]);
        accf[n * 17 + k] = sum;
    }
    __syncthreads();
    // h2 = relu(dinv*(accf @ W2) + b2); pool. 256 thr = 8 nodes x 32 cols
    int k = t & 31, l0 = t >> 5;
    for (int g = 0; g < 16; g++) {
        int n = l0 + g * 8, v = b * 128 + n;
        if (v < N_NODES) {
            const float* ar = &accf[n * 17];
            float a = 0.f;
#pragma unroll
            for (int j = 0; j < 16; j++) a += ar[j] * wl[j * 32 + k];
            float r = dinv[v] * a + b2[k];
            r = r > 0.f ? r : 0.f;
            int gg = lbat[n];
            atomicAdd(&lsum[gg * 32 + k], __float2int_rn(r * SCALEP));
            if (k == 0) atomicAdd(&lcnt[gg], 1);
        }
    }
    __syncthreads();
    int last = 127; if (b * 128 + last > N_NODES - 1) last = N_NODES - 1 - b * 128;
    int gmin = lbat[0], gmax = lbat[last];
    int ng = gmax - gmin + 1;
    for (int i = t; i < ng * 32; i += 256) {
        int gg = gmin + (i >> 5);
        int iv = lsum[gg * 32 + (i & 31)];
        if (iv != 0) atomicAdd(&gsum[gg * 32 + (i & 31)], (float)iv * ISCALEP);
    }
    for (int i = t; i < ng; i += 256) {
        int iv = lcnt[gmin + i];
        if (iv != 0) atomicAdd(&gcnt[gmin + i], (float)iv);
    }
}

// ---------------- head: mean -> fc1(relu) -> fc2 ----------------
__global__ void head(const float* __restrict__ gsum, const float* __restrict__ gcnt,
                     const float* __restrict__ Wf1, const float* __restrict__ bf1,
                     const float* __restrict__ Wf2, const float* __restrict__ bf2,
                     float* __restrict__ out) {
    __shared__ float gm[64 * 32];
    __shared__ float f1[64 * 64];
    int t = threadIdx.x;  // 1024
    for (int i = t; i < 2048; i += 1024) {
        int g = i >> 5;
        float c = gcnt[g]; if (c < 1.f) c = 1.f;
        gm[i] = gsum[i] / c;
    }
    __syncthreads();
    for (int i = t; i < 4096; i += 1024) {
        int r = i >> 6, c = i & 63;
        float a = bf1[c];
#pragma unroll
        for (int j = 0; j < 32; j++) a += gm[r * 32 + j] * Wf1[j * 64 + c];
        f1[i] = a > 0.f ? a : 0.f;
    }
    __syncthreads();
    if (t < 512) {
        int r = t >> 3, c = t & 7;
        float a = bf2[c];
#pragma unroll
        for (int j = 0; j < 64; j++) a += f1[r * 64 + j] * Wf2[j * 8 + c];
        out[t] = a;
    }
}

extern "C" void kernel_launch(void* const* d_in, const int* in_sizes, int n_in,
                              void* d_out, int out_size, void* d_ws, size_t ws_size,
                              hipStream_t stream) {
    const float* x   = (const float*)d_in[0];
    const int*   ei  = (const int*)d_in[1];
    const int*   bat = (const int*)d_in[2];
    const float* W1  = (const float*)d_in[3];
    const float* b1  = (const float*)d_in[4];
    const float* W2  = (const float*)d_in[5];
    const float* b2  = (const float*)d_in[6];
    const float* Wf1 = (const float*)d_in[7];
    const float* bf1 = (const float*)d_in[8];
    const float* Wf2 = (const float*)d_in[9];
    const float* bf2 = (const float*)d_in[10];
    const int* src = ei;
    const int* dst = ei + N_EDGES;
    float* out = (float*)d_out;

    // ---- workspace layout (~21.6 MB) ----
    char* ws = (char*)d_ws;
    unsigned int* stage = (unsigned int*)(ws + 0);          // 14,413,824 B
    float*        dinv  = (float*)       (ws + 14413824);   //    400,000 B
    __half*       hs1   = (__half*)      (ws + 14813824);   //  3,200,000 B (fp16)
    __half*       d1    = (__half*)      (ws + 18013824);   //  3,200,000 B (fp16)
    float*        gsum  = (float*)       (ws + 21213824);   //      8,192 B
    float*        gcnt  = (float*)       (ws + 21222016);   //        256 B
    int*          degG  = (int*)         (ws + 21222272);   //    400,000 B
    int*          bcnt  = (int*)         (ws + 21622272);   //      3,128 B
    // gsum..bcnt contiguous -> single memset of 411,576 B

    hipMemsetAsync(gsum, 0, 411576, stream);

    // single-pass binning (order-free: int accumulation is exact) + degrees
    place_direct<<<N_EDGES / 1024, 256, 0, stream>>>(src, dst, stage, degG, bcnt);

    // layer 1 (mm1 computes dinv from degG)
    mm1<<<(N_NODES + MM1_ROWS - 1) / MM1_ROWS, 256, 0, stream>>>(x, W1, degG, dinv, hs1);
    gather1<<<NBUCK, 256, 0, stream>>>(stage, bcnt, hs1, dinv, b1, d1);

    // layer 2 (16-dim aggregation; mm2 + relu + pool fused in epilogue)
    gather2<<<NBUCK, 256, 0, stream>>>(stage, bcnt, d1, dinv, W2, b2, bat, gsum, gcnt);

    // head
    head<<<1, 1024, 0, stream>>>(gsum, gcnt, Wf1, bf1, Wf2, bf2, out);
}

// Round 3
// 233.407 us; speedup vs baseline: 4.5282x; 4.5282x over previous
//
#include <hip/hip_runtime.h>
#include <hip/hip_fp16.h>

#define N_NODES  100000
#define N_EDGES  3200000
#define N_GRAPHS 64

#define BSHIFT   7
#define NBUCK    782          // ceil(N_NODES / 128)
#define CAP      4608         // mean 4096 + 8 sigma; overflow guarded (dropped)
#define PB_BLK   1024
#define PB_CHUNK 3125         // N_EDGES / PB_BLK exactly

#define SCALE1   2097152.0f   // 2^21 fixed-point for layer-1 accumulation
#define ISCALE1  (1.0f / 2097152.0f)
#define SCALE2   1048576.0f   // 2^20 for layer-2 (post-relu sums are larger)
#define ISCALE2  (1.0f / 1048576.0f)
#define SCALEP   65536.0f     // 2^16 for pooling partial sums (int LDS atomics)
#define ISCALEP  (1.0f / 65536.0f)

// R16: REVERT single-pass binning. R15's place_direct did 3.2M returning
// atomics on 782 counters (~4090 same-address each x ~200ns = 855us measured,
// VALUBusy 0.13%). The 3-pass hist/scan/place structure exists to have ZERO
// contended global atomics. Kept from R15: vectorized mm1, 16-edge gather
// batching, int fixed-point LDS pooling.

// shared edge-accumulate body for gather1/gather2 (int fixed-point LDS atomics)
#define EDGEACC(p_, r_, SC) { \
    int d_ = (int)((p_) >> 17); \
    float2 f01_ = __half22float2(*(const __half2*)&(r_).x); \
    float2 f23_ = __half22float2(*(const __half2*)&(r_).y); \
    int* a_ = &acc[d_ * 17 + f4 * 4]; \
    atomicAdd(a_ + 0, __float2int_rn(f01_.x * (SC))); \
    atomicAdd(a_ + 1, __float2int_rn(f01_.y * (SC))); \
    atomicAdd(a_ + 2, __float2int_rn(f23_.x * (SC))); \
    atomicAdd(a_ + 3, __float2int_rn(f23_.y * (SC))); }

// ---------------- pass 1: per-block 782-bucket histogram ----------------
__global__ void __launch_bounds__(256) hist_pass(const int* __restrict__ dst,
                                                 unsigned int* __restrict__ histG) {
    __shared__ int hist[NBUCK];
    int t = threadIdx.x;
    int e0 = blockIdx.x * PB_CHUNK;
    for (int i = t; i < NBUCK; i += 256) hist[i] = 0;
    __syncthreads();
    int i = t;
    for (; i + 768 < PB_CHUNK; i += 1024) {   // 4 loads in flight
        int a0 = dst[e0 + i];
        int a1 = dst[e0 + i + 256];
        int a2 = dst[e0 + i + 512];
        int a3 = dst[e0 + i + 768];
        atomicAdd(&hist[a0 >> BSHIFT], 1);
        atomicAdd(&hist[a1 >> BSHIFT], 1);
        atomicAdd(&hist[a2 >> BSHIFT], 1);
        atomicAdd(&hist[a3 >> BSHIFT], 1);
    }
    for (; i < PB_CHUNK; i += 256)
        atomicAdd(&hist[dst[e0 + i] >> BSHIFT], 1);
    __syncthreads();
    for (int i2 = t; i2 < NBUCK; i2 += 256)
        histG[blockIdx.x * NBUCK + i2] = (unsigned int)hist[i2];
}

// ---------------- pass 2: per-bucket scan over blocks -> deterministic bases --
__global__ void __launch_bounds__(256) scan_pass(const unsigned int* __restrict__ histG,
                                                 unsigned int* __restrict__ baseG,
                                                 int* __restrict__ cntG) {
    __shared__ unsigned int s[256];
    int b = blockIdx.x, t = threadIdx.x;
    unsigned int v0 = histG[(t * 4 + 0) * NBUCK + b];
    unsigned int v1 = histG[(t * 4 + 1) * NBUCK + b];
    unsigned int v2 = histG[(t * 4 + 2) * NBUCK + b];
    unsigned int v3 = histG[(t * 4 + 3) * NBUCK + b];
    unsigned int tot = v0 + v1 + v2 + v3;
    s[t] = tot;
    __syncthreads();
    for (int o = 1; o < 256; o <<= 1) {
        unsigned int x = (t >= o) ? s[t - o] : 0;
        __syncthreads();
        s[t] += x;
        __syncthreads();
    }
    unsigned int ex = s[t] - tot;
    unsigned int base = (unsigned int)b * CAP + ex;
    baseG[b * PB_BLK + t * 4 + 0] = base;
    baseG[b * PB_BLK + t * 4 + 1] = base + v0;
    baseG[b * PB_BLK + t * 4 + 2] = base + v0 + v1;
    baseG[b * PB_BLK + t * 4 + 3] = base + v0 + v1 + v2;
    if (t == 255) cntG[b] = (int)(ex + tot);
}

// ---------------- pass 3: LDS counting-sort + flat write-out (no atomics) ----
#define PLACE1(d_, s_) { \
    int bb_ = (d_) >> BSHIFT; \
    unsigned int pk_ = ((unsigned int)((d_) & 127) << 17) | (unsigned int)(s_); \
    int slot_ = atomicAdd(&cur[bb_], 1); \
    st[slot_] = pk_; bkt[slot_] = (unsigned short)bb_; }

__global__ void __launch_bounds__(256) place_pass(const int* __restrict__ src,
                                                  const int* __restrict__ dst,
                                                  const unsigned int* __restrict__ histG,
                                                  const unsigned int* __restrict__ baseG,
                                                  unsigned int* __restrict__ stage) {
    __shared__ int off[NBUCK];
    __shared__ int cur[NBUCK];
    __shared__ unsigned int gbase[NBUCK];
    __shared__ int part[256];
    __shared__ unsigned int st[PB_CHUNK];
    __shared__ unsigned short bkt[PB_CHUNK];
    int t = threadIdx.x, blk = blockIdx.x;
    int e0 = blk * PB_CHUNK;

    int b4 = t * 4;
    int h0 = (b4 + 0 < NBUCK) ? (int)histG[blk * NBUCK + b4 + 0] : 0;
    int h1 = (b4 + 1 < NBUCK) ? (int)histG[blk * NBUCK + b4 + 1] : 0;
    int h2 = (b4 + 2 < NBUCK) ? (int)histG[blk * NBUCK + b4 + 2] : 0;
    int h3 = (b4 + 3 < NBUCK) ? (int)histG[blk * NBUCK + b4 + 3] : 0;
    int tot = h0 + h1 + h2 + h3;
    part[t] = tot;
    __syncthreads();
    for (int o = 1; o < 256; o <<= 1) {
        int v = (t >= o) ? part[t - o] : 0;
        __syncthreads();
        part[t] += v;
        __syncthreads();
    }
    int ex = part[t] - tot;
    if (b4 + 0 < NBUCK) { off[b4 + 0] = ex;                cur[b4 + 0] = ex; }
    if (b4 + 1 < NBUCK) { off[b4 + 1] = ex + h0;           cur[b4 + 1] = ex + h0; }
    if (b4 + 2 < NBUCK) { off[b4 + 2] = ex + h0 + h1;      cur[b4 + 2] = ex + h0 + h1; }
    if (b4 + 3 < NBUCK) { off[b4 + 3] = ex + h0 + h1 + h2; cur[b4 + 3] = ex + h0 + h1 + h2; }
    for (int i = t; i < NBUCK; i += 256) gbase[i] = baseG[i * PB_BLK + blk];
    __syncthreads();

    int i = t;
    for (; i + 768 < PB_CHUNK; i += 1024) {   // 8 loads in flight
        int d0 = dst[e0 + i],        s0 = src[e0 + i];
        int d1_ = dst[e0 + i + 256], s1_ = src[e0 + i + 256];
        int d2_ = dst[e0 + i + 512], s2_ = src[e0 + i + 512];
        int d3_ = dst[e0 + i + 768], s3_ = src[e0 + i + 768];
        PLACE1(d0, s0); PLACE1(d1_, s1_); PLACE1(d2_, s2_); PLACE1(d3_, s3_);
    }
    for (; i < PB_CHUNK; i += 256) {
        int d = dst[e0 + i], sv = src[e0 + i];
        PLACE1(d, sv);
    }
    __syncthreads();

    for (int i2 = t; i2 < PB_CHUNK; i2 += 256) {
        int b = bkt[i2];
        unsigned int gs = gbase[b] + (unsigned int)(i2 - off[b]);
        if (gs < (unsigned int)(b + 1) * CAP) stage[gs] = st[i2];  // overflow dropped
    }
}

// ---------------- per-bucket degree -> dinv ----------
__global__ void __launch_bounds__(256) bucket_dinv(const unsigned int* __restrict__ stage,
                                                   const int* __restrict__ cntG,
                                                   float* __restrict__ dinv) {
    __shared__ int ldeg[128];
    int b = blockIdx.x, t = threadIdx.x;
    int base = b * CAP;
    int cnt = cntG[b]; if (cnt > CAP) cnt = CAP;
    if (t < 128) ldeg[t] = 0;
    __syncthreads();
    int i0 = t * 4;
    for (; i0 + 4 <= cnt; i0 += 1024) {       // uint4 = 4 edges/lane/iter
        uint4 p = *(const uint4*)(stage + base + i0);
        atomicAdd(&ldeg[p.x >> 17], 1);
        atomicAdd(&ldeg[p.y >> 17], 1);
        atomicAdd(&ldeg[p.z >> 17], 1);
        atomicAdd(&ldeg[p.w >> 17], 1);
    }
    for (int j = i0; j < cnt && j < i0 + 4; j++)
        atomicAdd(&ldeg[stage[base + j] >> 17], 1);
    __syncthreads();
    int v = b * 128 + t;
    if (t < 128 && v < N_NODES) dinv[v] = rsqrtf((float)(ldeg[t] + 1));  // +1 self loop
}

// ---------------- layer-1 matmul: hs1 = fp16( (x @ W1) * dinv ) ----------------
// R15: 64 rows/block, 4 outputs/thread via b128 W reads (4x fewer LDS instrs).
#define MM1_ROWS 64
__global__ void __launch_bounds__(256) mm1(const float* __restrict__ x,
                                           const float* __restrict__ W,
                                           const float* __restrict__ dinv,
                                           __half* __restrict__ hs) {
    __shared__ float ws[128 * 16];
    __shared__ float xs[MM1_ROWS * 132];   // pad 132: 16B-aligned, 2-way bank (free)
    int t = threadIdx.x;
    int row0 = blockIdx.x * MM1_ROWS;
    for (int i = t; i < 2048; i += 256) ws[i] = W[i];
    for (int i = t; i < 2048; i += 256) {             // 2048 float4 = 64 rows x 128
        int r = i >> 5, c4 = (i & 31) * 4;
        int v = row0 + r;
        float4 val = (v < N_NODES) ? *(const float4*)(x + (size_t)v * 128 + c4)
                                   : make_float4(0.f, 0.f, 0.f, 0.f);
        *(float4*)&xs[r * 132 + c4] = val;
    }
    __syncthreads();
    int row = t >> 2, c4 = (t & 3) * 4;
    int v = row0 + row;
    if (v < N_NODES) {
        float dv = dinv[v];
        float a0 = 0.f, a1 = 0.f, a2 = 0.f, a3 = 0.f;
#pragma unroll
        for (int k = 0; k < 128; k++) {
            float xv = xs[row * 132 + k];
            float4 w4 = *(const float4*)&ws[k * 16 + c4];
            a0 += xv * w4.x; a1 += xv * w4.y; a2 += xv * w4.z; a3 += xv * w4.w;
        }
        __half2 h01 = __floats2half2_rn(a0 * dv, a1 * dv);
        __half2 h23 = __floats2half2_rn(a2 * dv, a3 * dv);
        uint2 o = make_uint2(*(unsigned*)&h01, *(unsigned*)&h23);
        *(uint2*)(hs + (size_t)v * 16 + c4) = o;      // 8B store
    }
}

// ---------------- layer-1 gather: edge-parallel, FIXED-POINT int LDS atomics --
// R13: int atomicAdd is native ds_add_u32. R15: 16-edge batching per quad.
__global__ void __launch_bounds__(256) gather1(const unsigned int* __restrict__ stage,
                                               const int* __restrict__ cntG,
                                               const __half* __restrict__ hs,
                                               const float* __restrict__ dinv,
                                               const float* __restrict__ b1,
                                               __half* __restrict__ d1) {
    __shared__ int acc[128 * 17];   // +1 pad spreads d*16 bank aliasing
    int b = blockIdx.x, t = threadIdx.x;
    int base = b * CAP;
    int cnt = cntG[b]; if (cnt > CAP) cnt = CAP;
    for (int i = t; i < 128 * 17; i += 256) acc[i] = 0;
    __syncthreads();
    int f4 = t & 3;
    int q = t >> 2;
    int i0 = q * 16;
    for (; i0 + 16 <= cnt; i0 += 1024) {
        const uint4* sp = (const uint4*)(stage + base + i0);  // 16B-aligned
        uint4 pa = sp[0], pb = sp[1], pc = sp[2], pd = sp[3]; // quad-broadcast
        uint2 r0  = *(const uint2*)(hs + (pa.x & 0x1FFFF) * 16 + f4 * 4);
        uint2 r1  = *(const uint2*)(hs + (pa.y & 0x1FFFF) * 16 + f4 * 4);
        uint2 r2  = *(const uint2*)(hs + (pa.z & 0x1FFFF) * 16 + f4 * 4);
        uint2 r3  = *(const uint2*)(hs + (pa.w & 0x1FFFF) * 16 + f4 * 4);
        uint2 r4  = *(const uint2*)(hs + (pb.x & 0x1FFFF) * 16 + f4 * 4);
        uint2 r5  = *(const uint2*)(hs + (pb.y & 0x1FFFF) * 16 + f4 * 4);
        uint2 r6  = *(const uint2*)(hs + (pb.z & 0x1FFFF) * 16 + f4 * 4);
        uint2 r7  = *(const uint2*)(hs + (pb.w & 0x1FFFF) * 16 + f4 * 4);
        uint2 r8  = *(const uint2*)(hs + (pc.x & 0x1FFFF) * 16 + f4 * 4);
        uint2 r9  = *(const uint2*)(hs + (pc.y & 0x1FFFF) * 16 + f4 * 4);
        uint2 r10 = *(const uint2*)(hs + (pc.z & 0x1FFFF) * 16 + f4 * 4);
        uint2 r11 = *(const uint2*)(hs + (pc.w & 0x1FFFF) * 16 + f4 * 4);
        uint2 r12 = *(const uint2*)(hs + (pd.x & 0x1FFFF) * 16 + f4 * 4);
        uint2 r13 = *(const uint2*)(hs + (pd.y & 0x1FFFF) * 16 + f4 * 4);
        uint2 r14 = *(const uint2*)(hs + (pd.z & 0x1FFFF) * 16 + f4 * 4);
        uint2 r15 = *(const uint2*)(hs + (pd.w & 0x1FFFF) * 16 + f4 * 4);
        EDGEACC(pa.x, r0,  SCALE1); EDGEACC(pa.y, r1,  SCALE1);
        EDGEACC(pa.z, r2,  SCALE1); EDGEACC(pa.w, r3,  SCALE1);
        EDGEACC(pb.x, r4,  SCALE1); EDGEACC(pb.y, r5,  SCALE1);
        EDGEACC(pb.z, r6,  SCALE1); EDGEACC(pb.w, r7,  SCALE1);
        EDGEACC(pc.x, r8,  SCALE1); EDGEACC(pc.y, r9,  SCALE1);
        EDGEACC(pc.z, r10, SCALE1); EDGEACC(pc.w, r11, SCALE1);
        EDGEACC(pd.x, r12, SCALE1); EDGEACC(pd.y, r13, SCALE1);
        EDGEACC(pd.z, r14, SCALE1); EDGEACC(pd.w, r15, SCALE1);
    }
    for (int j = i0; j < cnt && j < i0 + 16; j++) {           // residual window
        unsigned int p = stage[base + j];
        uint2 r = *(const uint2*)(hs + (p & 0x1FFFF) * 16 + f4 * 4);
        EDGEACC(p, r, SCALE1);
    }
    __syncthreads();
    for (int i = t; i < 2048; i += 256) {
        int n = i >> 4, k = i & 15, v = b * 128 + n;
        if (v < N_NODES) {
            float dv = dinv[v];
            float sum = (float)acc[n * 17 + k] * ISCALE1;
            float self = __half2float(hs[v * 16 + k]);
            float r = dv * (sum + self) + b1[k];
            d1[v * 16 + k] = __float2half(r > 0.f ? dv * r : 0.f);
        }
    }
}

// ---------------- layer-2 gather + mm2 + relu + mean-pool, fused --------------
__global__ void __launch_bounds__(256) gather2(const unsigned int* __restrict__ stage,
                                               const int* __restrict__ cntG,
                                               const __half* __restrict__ d1,
                                               const float* __restrict__ dinv,
                                               const float* __restrict__ W2,
                                               const float* __restrict__ b2,
                                               const int* __restrict__ batch,
                                               float* __restrict__ gsum,
                                               float* __restrict__ gcnt) {
    __shared__ int acc[128 * 17];
    __shared__ float wl[512];
    __shared__ int lsum[N_GRAPHS * 32];   // int fixed-point (native ds_add)
    __shared__ int lcnt[N_GRAPHS];
    __shared__ int lbat[128];
    float* accf = (float*)acc;   // reused as float after conversion pass
    int b = blockIdx.x, t = threadIdx.x;
    int base = b * CAP;
    int cnt = cntG[b]; if (cnt > CAP) cnt = CAP;
    for (int i = t; i < 128 * 17; i += 256) acc[i] = 0;
    for (int i = t; i < 512; i += 256) wl[i] = W2[i];
    for (int i = t; i < N_GRAPHS * 32; i += 256) lsum[i] = 0;
    if (t < N_GRAPHS) lcnt[t] = 0;
    if (t < 128) {
        int v = b * 128 + t;
        lbat[t] = (v < N_NODES) ? batch[v] : 0;
    }
    __syncthreads();
    int f4 = t & 3;
    int q = t >> 2;
    int i0 = q * 16;
    for (; i0 + 16 <= cnt; i0 += 1024) {
        const uint4* sp = (const uint4*)(stage + base + i0);
        uint4 pa = sp[0], pb = sp[1], pc = sp[2], pd = sp[3];
        uint2 r0  = *(const uint2*)(d1 + (pa.x & 0x1FFFF) * 16 + f4 * 4);
        uint2 r1  = *(const uint2*)(d1 + (pa.y & 0x1FFFF) * 16 + f4 * 4);
        uint2 r2  = *(const uint2*)(d1 + (pa.z & 0x1FFFF) * 16 + f4 * 4);
        uint2 r3  = *(const uint2*)(d1 + (pa.w & 0x1FFFF) * 16 + f4 * 4);
        uint2 r4  = *(const uint2*)(d1 + (pb.x & 0x1FFFF) * 16 + f4 * 4);
        uint2 r5  = *(const uint2*)(d1 + (pb.y & 0x1FFFF) * 16 + f4 * 4);
        uint2 r6  = *(const uint2*)(d1 + (pb.z & 0x1FFFF) * 16 + f4 * 4);
        uint2 r7  = *(const uint2*)(d1 + (pb.w & 0x1FFFF) * 16 + f4 * 4);
        uint2 r8  = *(const uint2*)(d1 + (pc.x & 0x1FFFF) * 16 + f4 * 4);
        uint2 r9  = *(const uint2*)(d1 + (pc.y & 0x1FFFF) * 16 + f4 * 4);
        uint2 r10 = *(const uint2*)(d1 + (pc.z & 0x1FFFF) * 16 + f4 * 4);
        uint2 r11 = *(const uint2*)(d1 + (pc.w & 0x1FFFF) * 16 + f4 * 4);
        uint2 r12 = *(const uint2*)(d1 + (pd.x & 0x1FFFF) * 16 + f4 * 4);
        uint2 r13 = *(const uint2*)(d1 + (pd.y & 0x1FFFF) * 16 + f4 * 4);
        uint2 r14 = *(const uint2*)(d1 + (pd.z & 0x1FFFF) * 16 + f4 * 4);
        uint2 r15 = *(const uint2*)(d1 + (pd.w & 0x1FFFF) * 16 + f4 * 4);
        EDGEACC(pa.x, r0,  SCALE2); EDGEACC(pa.y, r1,  SCALE2);
        EDGEACC(pa.z, r2,  SCALE2); EDGEACC(pa.w, r3,  SCALE2);
        EDGEACC(pb.x, r4,  SCALE2); EDGEACC(pb.y, r5,  SCALE2);
        EDGEACC(pb.z, r6,  SCALE2); EDGEACC(pb.w, r7,  SCALE2);
        EDGEACC(pc.x, r8,  SCALE2); EDGEACC(pc.y, r9,  SCALE2);
        EDGEACC(pc.z, r10, SCALE2); EDGEACC(pc.w, r11, SCALE2);
        EDGEACC(pd.x, r12, SCALE2); EDGEACC(pd.y, r13, SCALE2);
        EDGEACC(pd.z, r14, SCALE2); EDGEACC(pd.w, r15, SCALE2);
    }
    for (int j = i0; j < cnt && j < i0 + 16; j++) {
        unsigned int p = stage[base + j];
        uint2 r = *(const uint2*)(d1 + (p & 0x1FFFF) * 16 + f4 * 4);
        EDGEACC(p, r, SCALE2);
    }
    __syncthreads();
    // convert int->float in place and add self-loop term
    for (int i = t; i < 2048; i += 256) {
        int n = i >> 4, k = i & 15, v = b * 128 + n;
        float sum = (float)acc[n * 17 + k] * ISCALE2;
        if (v < N_NODES) sum += __half2float(d1[v * 16 + k]);
        accf[n * 17 + k] = sum;
    }
    __syncthreads();
    // h2 = relu(dinv*(accf @ W2) + b2); pool. 256 thr = 8 nodes x 32 cols
    int k = t & 31, l0 = t >> 5;
    for (int g = 0; g < 16; g++) {
        int n = l0 + g * 8, v = b * 128 + n;
        if (v < N_NODES) {
            const float* ar = &accf[n * 17];
            float a = 0.f;
#pragma unroll
            for (int j = 0; j < 16; j++) a += ar[j] * wl[j * 32 + k];
            float r = dinv[v] * a + b2[k];
            r = r > 0.f ? r : 0.f;
            int gg = lbat[n];
            atomicAdd(&lsum[gg * 32 + k], __float2int_rn(r * SCALEP));
            if (k == 0) atomicAdd(&lcnt[gg], 1);
        }
    }
    __syncthreads();
    int last = 127; if (b * 128 + last > N_NODES - 1) last = N_NODES - 1 - b * 128;
    int gmin = lbat[0], gmax = lbat[last];
    int ng = gmax - gmin + 1;
    for (int i = t; i < ng * 32; i += 256) {
        int gg = gmin + (i >> 5);
        int iv = lsum[gg * 32 + (i & 31)];
        if (iv != 0) atomicAdd(&gsum[gg * 32 + (i & 31)], (float)iv * ISCALEP);
    }
    for (int i = t; i < ng; i += 256) {
        int iv = lcnt[gmin + i];
        if (iv != 0) atomicAdd(&gcnt[gmin + i], (float)iv);
    }
}

// ---------------- head: mean -> fc1(relu) -> fc2 ----------------
__global__ void head(const float* __restrict__ gsum, const float* __restrict__ gcnt,
                     const float* __restrict__ Wf1, const float* __restrict__ bf1,
                     const float* __restrict__ Wf2, const float* __restrict__ bf2,
                     float* __restrict__ out) {
    __shared__ float gm[64 * 32];
    __shared__ float f1[64 * 64];
    int t = threadIdx.x;  // 1024
    for (int i = t; i < 2048; i += 1024) {
        int g = i >> 5;
        float c = gcnt[g]; if (c < 1.f) c = 1.f;
        gm[i] = gsum[i] / c;
    }
    __syncthreads();
    for (int i = t; i < 4096; i += 1024) {
        int r = i >> 6, c = i & 63;
        float a = bf1[c];
#pragma unroll
        for (int j = 0; j < 32; j++) a += gm[r * 32 + j] * Wf1[j * 64 + c];
        f1[i] = a > 0.f ? a : 0.f;
    }
    __syncthreads();
    if (t < 512) {
        int r = t >> 3, c = t & 7;
        float a = bf2[c];
#pragma unroll
        for (int j = 0; j < 64; j++) a += f1[r * 64 + j] * Wf2[j * 8 + c];
        out[t] = a;
    }
}

extern "C" void kernel_launch(void* const* d_in, const int* in_sizes, int n_in,
                              void* d_out, int out_size, void* d_ws, size_t ws_size,
                              hipStream_t stream) {
    const float* x   = (const float*)d_in[0];
    const int*   ei  = (const int*)d_in[1];
    const int*   bat = (const int*)d_in[2];
    const float* W1  = (const float*)d_in[3];
    const float* b1  = (const float*)d_in[4];
    const float* W2  = (const float*)d_in[5];
    const float* b2  = (const float*)d_in[6];
    const float* Wf1 = (const float*)d_in[7];
    const float* bf1 = (const float*)d_in[8];
    const float* Wf2 = (const float*)d_in[9];
    const float* bf2 = (const float*)d_in[10];
    const int* src = ei;
    const int* dst = ei + N_EDGES;
    float* out = (float*)d_out;

    // ---- workspace layout (~27.6 MB) ----
    char* ws = (char*)d_ws;
    unsigned int* histG = (unsigned int*)(ws + 0);          //  3,202,048 B
    unsigned int* baseG = (unsigned int*)(ws + 3202048);    //  3,202,048 B
    int*          cntG  = (int*)         (ws + 6404096);    //      3,128 B (pad 4K)
    unsigned int* stage = (unsigned int*)(ws + 6408192);    // 14,413,824 B
    float*        dinv  = (float*)       (ws + 20822016);   //    400,000 B
    float*        gsum  = (float*)       (ws + 21222016);   //      8,192 B
    float*        gcnt  = (float*)       (ws + 21230208);   //        256 B
    __half*       hs1   = (__half*)      (ws + 21230464);   //  3,200,000 B (fp16)
    __half*       d1    = (__half*)      (ws + 24430464);   //  3,200,000 B (fp16)

    hipMemsetAsync(gsum, 0, (N_GRAPHS * 32 + N_GRAPHS) * sizeof(float), stream);

    // CSR-free build: deterministic binning (zero contended global atomics)
    hist_pass<<<PB_BLK, 256, 0, stream>>>(dst, histG);
    scan_pass<<<NBUCK, 256, 0, stream>>>(histG, baseG, cntG);
    place_pass<<<PB_BLK, 256, 0, stream>>>(src, dst, histG, baseG, stage);
    bucket_dinv<<<NBUCK, 256, 0, stream>>>(stage, cntG, dinv);

    // layer 1
    mm1<<<(N_NODES + MM1_ROWS - 1) / MM1_ROWS, 256, 0, stream>>>(x, W1, dinv, hs1);
    gather1<<<NBUCK, 256, 0, stream>>>(stage, cntG, hs1, dinv, b1, d1);

    // layer 2 (16-dim aggregation; mm2 + relu + pool fused in epilogue)
    gather2<<<NBUCK, 256, 0, stream>>>(stage, cntG, d1, dinv, W2, b2, bat, gsum, gcnt);

    // head
    head<<<1, 1024, 0, stream>>>(gsum, gcnt, Wf1, bf1, Wf2, bf2, out);
}